// Round 1
// baseline (545.856 us; speedup 1.0000x reference)
//
#include <hip/hip_runtime.h>

typedef float f32x4 __attribute__((ext_vector_type(4)));
typedef short bf16x8 __attribute__((ext_vector_type(8)));
typedef short s16x4 __attribute__((ext_vector_type(4)));
typedef unsigned short u16;

#define B_ 8
#define C_ 512
#define N_ 4096
#define M_ 1024
#define P_ 128
// 1 / (sqrt(128) * 0.05)
#define INV_ST 1.7677669529663689f

__device__ __forceinline__ u16 f2b(float f) {
  unsigned u = __float_as_uint(f);
  u += 0x7fffu + ((u >> 16) & 1u);   // RNE; inputs finite
  return (u16)(u >> 16);
}
__device__ __forceinline__ float b2f(u16 h) {
  return __uint_as_float(((unsigned)h) << 16);
}
__device__ __forceinline__ float waveRedSum(float v) {
#pragma unroll
  for (int off = 32; off > 0; off >>= 1) v += __shfl_xor(v, off);
  return v;
}

// ---------------------------------------------------------------------------
// Kernel 1: per-(b,c) plane: maxpool 2x2 -> xd (fp32), spatial means of x, xd
// ---------------------------------------------------------------------------
__global__ __launch_bounds__(256) void prep_pool(const float* __restrict__ x,
                                                 float* __restrict__ xd,
                                                 float* __restrict__ meanx,
                                                 float* __restrict__ meanxd) {
  const int bc = blockIdx.x;          // 0..4095 = b*512 + c
  const int tid = threadIdx.x;
  const int lane = tid & 63, wid = tid >> 6;
  const float* xp = x + (size_t)bc * 4096;
  float* xdp = xd + (size_t)bc * 1024;
  __shared__ float xs[4096];
  __shared__ float w4[4], w4b[4];
  float s = 0.f;
#pragma unroll
  for (int i = 0; i < 16; ++i) {
    float v = xp[i * 256 + tid];
    xs[i * 256 + tid] = v;
    s += v;
  }
  s = waveRedSum(s);
  if (lane == 0) w4[wid] = s;
  __syncthreads();
  if (tid == 0) meanx[bc] = (w4[0] + w4[1] + w4[2] + w4[3]) * (1.f / 4096.f);
  float sd = 0.f;
#pragma unroll
  for (int i = 0; i < 4; ++i) {
    int mp = i * 256 + tid;               // pooled index 0..1023
    int r2 = mp >> 5, c2 = mp & 31;
    const float* p0 = xs + r2 * 128 + c2 * 2;
    float v = fmaxf(fmaxf(p0[0], p0[1]), fmaxf(p0[64], p0[65]));
    xdp[mp] = v;
    sd += v;
  }
  sd = waveRedSum(sd);
  if (lane == 0) w4b[wid] = sd;
  __syncthreads();
  if (tid == 0) meanxd[bc] = (w4b[0] + w4b[1] + w4b[2] + w4b[3]) * (1.f / 1024.f);
}

// ---------------------------------------------------------------------------
// Kernel 2: fp32 -> bf16 for wq (65536), wk (65536), wv (262144)
// ---------------------------------------------------------------------------
__global__ __launch_bounds__(256) void f2bf3(const float* __restrict__ a,
                                             const float* __restrict__ b,
                                             const float* __restrict__ c,
                                             u16* __restrict__ oa,
                                             u16* __restrict__ ob,
                                             u16* __restrict__ oc) {
  int i = blockIdx.x * 256 + threadIdx.x;
  if (i < 65536) oa[i] = f2b(a[i]);
  else if (i < 131072) ob[i - 65536] = f2b(b[i - 65536]);
  else if (i < 393216) oc[i - 131072] = f2b(c[i - 131072]);
}

// ---------------------------------------------------------------------------
// Kernel 3: GEMM  D[row=co][col=n] = sum_c A[co][c] * (B[b][c][n] - mean[b][c])
// A: bf16 [Cout][512].  B: fp32 [B][512][Ncols].  out bf16:
//   TRANS:  out[b][n][co]   (used for q: [b][n][p] and k^T: [b][m][p])
//   else :  out[b][co][n]   (used for v: [b][c][m])
// 64x64 tile, BK=64, 4 waves (2x2), LDS A[64][72] + B^T[64][72] (2-way max).
// ---------------------------------------------------------------------------
template <bool TRANS, bool SUBMEAN>
__global__ __launch_bounds__(256) void gemm_wx(const u16* __restrict__ A,
                                               const float* __restrict__ Bsrc,
                                               const float* __restrict__ mean,
                                               u16* __restrict__ outp,
                                               int Cout, int Ncols) {
  const int b = blockIdx.z;
  const int col0 = blockIdx.x * 64;
  const int row0 = blockIdx.y * 64;
  const int tid = threadIdx.x;
  const int lane = tid & 63, wid = tid >> 6;
  const int g = lane >> 4, c16 = lane & 15;
  const int wr = (wid >> 1) * 32, wc = (wid & 1) * 32;
  __shared__ __align__(16) u16 As[64][72];
  __shared__ __align__(16) u16 Bt[64][72];   // [col][k]
  const float* Bb = Bsrc + (size_t)b * 512 * Ncols;
  const float* mb = SUBMEAN ? (mean + b * 512) : nullptr;
  f32x4 acc[2][2];
#pragma unroll
  for (int i = 0; i < 2; ++i)
#pragma unroll
    for (int j = 0; j < 2; ++j) acc[i][j] = (f32x4){0.f, 0.f, 0.f, 0.f};

  for (int k0 = 0; k0 < 512; k0 += 64) {
    // stage A tile [64 rows][64 k]
#pragma unroll
    for (int i = 0; i < 2; ++i) {
      int f = tid + i * 256;
      int r = f >> 3, c8 = f & 7;
      *(bf16x8*)&As[r][c8 * 8] =
          *(const bf16x8*)(A + (size_t)(row0 + r) * 512 + k0 + c8 * 8);
    }
    // stage B tile [64 k][64 n] fp32 -> transposed bf16 Bt[n][k]
#pragma unroll
    for (int i = 0; i < 4; ++i) {
      int f = tid + i * 256;
      int kr = f >> 4, n4 = (f & 15) * 4;
      const float* src = Bb + (size_t)(k0 + kr) * Ncols + col0 + n4;
      float4 val = *(const float4*)src;
      if (SUBMEAN) {
        float mv = mb[k0 + kr];
        val.x -= mv; val.y -= mv; val.z -= mv; val.w -= mv;
      }
      Bt[n4 + 0][kr] = f2b(val.x);
      Bt[n4 + 1][kr] = f2b(val.y);
      Bt[n4 + 2][kr] = f2b(val.z);
      Bt[n4 + 3][kr] = f2b(val.w);
    }
    __syncthreads();
#pragma unroll
    for (int kk = 0; kk < 2; ++kk) {
      bf16x8 af[2], bfr[2];
#pragma unroll
      for (int i = 0; i < 2; ++i)
        af[i] = *(const bf16x8*)&As[wr + i * 16 + c16][kk * 32 + g * 8];
#pragma unroll
      for (int j = 0; j < 2; ++j)
        bfr[j] = *(const bf16x8*)&Bt[wc + j * 16 + c16][kk * 32 + g * 8];
#pragma unroll
      for (int i = 0; i < 2; ++i)
#pragma unroll
        for (int j = 0; j < 2; ++j)
          acc[i][j] = __builtin_amdgcn_mfma_f32_16x16x32_bf16(af[i], bfr[j],
                                                              acc[i][j], 0, 0, 0);
    }
    __syncthreads();
  }
  // epilogue; D lane mapping: row = +g*4+r, col = +c16
  if (TRANS) {
#pragma unroll
    for (int i = 0; i < 2; ++i)
#pragma unroll
      for (int j = 0; j < 2; ++j) {
        int row = row0 + wr + i * 16 + g * 4;
        int col = col0 + wc + j * 16 + c16;
        s16x4 h;
#pragma unroll
        for (int r = 0; r < 4; ++r) h[r] = (short)f2b(acc[i][j][r]);
        *(s16x4*)(outp + ((size_t)b * Ncols + col) * Cout + row) = h;
      }
  } else {
#pragma unroll
    for (int i = 0; i < 2; ++i)
#pragma unroll
      for (int j = 0; j < 2; ++j) {
        int row = row0 + wr + i * 16 + g * 4;
        int col = col0 + wc + j * 16 + c16;
#pragma unroll
        for (int r = 0; r < 4; ++r)
          outp[((size_t)b * Cout + row + r) * Ncols + col] = f2b(acc[i][j][r]);
      }
  }
}

// ---------------------------------------------------------------------------
// Kernel 4: global-context branch. One block (1024 thr) per batch.
// logit[m] = sum_c wm[c]*xd[b][c][m] + bm; mask = softmax_m; gc[b][c] = v.mask
// ---------------------------------------------------------------------------
__global__ __launch_bounds__(1024) void mask_gc(const float* __restrict__ xd,
                                                const u16* __restrict__ v,
                                                const float* __restrict__ wm,
                                                const float* __restrict__ bmp,
                                                float* __restrict__ gc) {
  const int b = blockIdx.x, tid = threadIdx.x;
  const int lane = tid & 63, wid = tid >> 6;
  __shared__ float ml[1024];
  __shared__ float r16[16];
  __shared__ float sred[2];
  const float* xb = xd + (size_t)b * (512 * 1024);
  float a0 = 0, a1 = 0, a2 = 0, a3 = 0;
  for (int c = 0; c < 512; c += 4) {
    a0 += wm[c + 0] * xb[(size_t)(c + 0) * 1024 + tid];
    a1 += wm[c + 1] * xb[(size_t)(c + 1) * 1024 + tid];
    a2 += wm[c + 2] * xb[(size_t)(c + 2) * 1024 + tid];
    a3 += wm[c + 3] * xb[(size_t)(c + 3) * 1024 + tid];
  }
  float logit = (a0 + a1) + (a2 + a3) + bmp[0];
  float mx = logit;
#pragma unroll
  for (int off = 32; off > 0; off >>= 1) mx = fmaxf(mx, __shfl_xor(mx, off));
  if (lane == 0) r16[wid] = mx;
  __syncthreads();
  if (tid == 0) {
    float m = r16[0];
    for (int i = 1; i < 16; ++i) m = fmaxf(m, r16[i]);
    sred[0] = m;
  }
  __syncthreads();
  float p = __expf(logit - sred[0]);
  float sm = waveRedSum(p);
  if (lane == 0) r16[wid] = sm;
  ml[tid] = p;
  __syncthreads();
  if (tid == 0) {
    float s2 = 0;
    for (int i = 0; i < 16; ++i) s2 += r16[i];
    sred[1] = 1.0f / s2;
  }
  __syncthreads();
  const float inv = sred[1];
  // phase 2: gc[c] = (sum_m v[b][c][m]*p[m]) * inv ; 2 threads per c
  const int c = tid >> 1, half = tid & 1;
  const u16* vr = v + ((size_t)b * 512 + c) * 1024 + half * 512;
  const float* mlr = ml + half * 512;
  float s = 0;
  for (int i = 0; i < 64; ++i) {
    bf16x8 h = *(const bf16x8*)(vr + i * 8);
#pragma unroll
    for (int j = 0; j < 8; ++j) s += b2f((u16)h[j]) * mlr[i * 8 + j];
  }
  s += __shfl_xor(s, 1);
  if (half == 0) gc[b * 512 + c] = s * inv;
}

// ---------------------------------------------------------------------------
// Kernel 5: flash attention + epilogue (gamma*O/l + gc + x).
// Block = 4 waves, one 16-row Q tile; m-loop 16 steps of 64.
// sim: wave w computes S[16n][16m] at m-offset w*16 (A=q[n][p], B=k_t[m][p]).
// PV:  wave w owns c-slice w*128; A=v[c][m], B=P_lds[n][m]; D[row=c][col=n].
// ---------------------------------------------------------------------------
__global__ __launch_bounds__(256) void attn(const u16* __restrict__ q,
                                            const u16* __restrict__ kt,
                                            const u16* __restrict__ v,
                                            const float* __restrict__ gc,
                                            const float* __restrict__ x,
                                            const float* __restrict__ gamma,
                                            float* __restrict__ out) {
  const int b = blockIdx.y;
  const int n0 = blockIdx.x * 16;
  const int tid = threadIdx.x;
  const int lane = tid & 63, wid = tid >> 6;
  const int g = lane >> 4, c16 = lane & 15;
  __shared__ __align__(16) u16 Pl[16][72];
  __shared__ float m_run[16], l_run[16], scale_s[16], mnew_s[16];
  __shared__ float red[4][16];
  if (tid < 16) { m_run[tid] = -1e30f; l_run[tid] = 0.f; }
  bf16x8 qf[4];
  const u16* qrow = q + ((size_t)b * N_ + n0 + c16) * P_ + g * 8;
#pragma unroll
  for (int kf = 0; kf < 4; ++kf) qf[kf] = *(const bf16x8*)(qrow + kf * 32);
  f32x4 acc[8];
#pragma unroll
  for (int i = 0; i < 8; ++i) acc[i] = (f32x4){0.f, 0.f, 0.f, 0.f};
  const int cs = wid * 128;
  __syncthreads();

  for (int s = 0; s < 16; ++s) {
    const int m0 = s * 64;
    // ---- S tile (this wave's 16 m-columns) ----
    f32x4 sv = (f32x4){0.f, 0.f, 0.f, 0.f};
    const u16* krow = kt + ((size_t)b * M_ + m0 + wid * 16 + c16) * P_ + g * 8;
#pragma unroll
    for (int kf = 0; kf < 4; ++kf) {
      bf16x8 kk8 = *(const bf16x8*)(krow + kf * 32);
      sv = __builtin_amdgcn_mfma_f32_16x16x32_bf16(qf[kf], kk8, sv, 0, 0, 0);
    }
    float sr[4], mx[4];
#pragma unroll
    for (int r = 0; r < 4; ++r) {
      sr[r] = sv[r] * INV_ST;
      float t = sr[r];
#pragma unroll
      for (int off = 1; off <= 8; off <<= 1) t = fmaxf(t, __shfl_xor(t, off));
      mx[r] = t;
    }
    if (c16 == 0) {
#pragma unroll
      for (int r = 0; r < 4; ++r) red[wid][g * 4 + r] = mx[r];
    }
    __syncthreads();                                    // B1
    if (tid < 16) {
      float wm4 = fmaxf(fmaxf(red[0][tid], red[1][tid]),
                        fmaxf(red[2][tid], red[3][tid]));
      float mo = m_run[tid];
      float mn = fmaxf(mo, wm4);
      float sc = __expf(mo - mn);
      m_run[tid] = mn;
      mnew_s[tid] = mn;
      scale_s[tid] = sc;
      l_run[tid] *= sc;
    }
    __syncthreads();                                    // B2
    float p[4], rs[4];
#pragma unroll
    for (int r = 0; r < 4; ++r) {
      p[r] = __expf(sr[r] - mnew_s[g * 4 + r]);
      float t = p[r];
#pragma unroll
      for (int off = 1; off <= 8; off <<= 1) t += __shfl_xor(t, off);
      rs[r] = t;
    }
    if (c16 == 0) {
#pragma unroll
      for (int r = 0; r < 4; ++r) red[wid][g * 4 + r] = rs[r];
    }
#pragma unroll
    for (int r = 0; r < 4; ++r) Pl[g * 4 + r][wid * 16 + c16] = f2b(p[r]);
    const float scl = scale_s[c16];                     // O rows=c, cols=n=c16
#pragma unroll
    for (int cf = 0; cf < 8; ++cf) {
      acc[cf][0] *= scl; acc[cf][1] *= scl; acc[cf][2] *= scl; acc[cf][3] *= scl;
    }
    __syncthreads();                                    // B3
    if (tid < 16)
      l_run[tid] += red[0][tid] + red[1][tid] + red[2][tid] + red[3][tid];
    // ---- PV ----
#pragma unroll
    for (int kk = 0; kk < 2; ++kk) {
      bf16x8 pb = *(const bf16x8*)&Pl[c16][kk * 32 + g * 8];
      const u16* vbase = v + ((size_t)b * C_ + cs + c16) * M_ + m0 + kk * 32 + g * 8;
#pragma unroll
      for (int cf = 0; cf < 8; ++cf) {
        bf16x8 va = *(const bf16x8*)(vbase + (size_t)cf * 16 * M_);
        acc[cf] = __builtin_amdgcn_mfma_f32_16x16x32_bf16(va, pb, acc[cf], 0, 0, 0);
      }
    }
    __syncthreads();                                    // B4
  }

  const float linv = 1.0f / l_run[c16];
  const float gam = gamma[0];
#pragma unroll
  for (int cf = 0; cf < 8; ++cf) {
    const int c = cs + cf * 16 + g * 4;
#pragma unroll
    for (int r = 0; r < 4; ++r) {
      const size_t idx = ((size_t)b * C_ + c + r) * (size_t)N_ + n0 + c16;
      out[idx] = gam * acc[cf][r] * linv + gc[b * C_ + c + r] + x[idx];
    }
  }
}

// ---------------------------------------------------------------------------
extern "C" void kernel_launch(void* const* d_in, const int* in_sizes, int n_in,
                              void* d_out, int out_size, void* d_ws, size_t ws_size,
                              hipStream_t stream) {
  const float* x     = (const float*)d_in[0];
  const float* wq    = (const float*)d_in[1];
  const float* wk    = (const float*)d_in[3];
  const float* wv    = (const float*)d_in[5];
  const float* wm    = (const float*)d_in[6];
  const float* bm    = (const float*)d_in[7];
  const float* gamma = (const float*)d_in[8];
  float* out = (float*)d_out;
  char* ws = (char*)d_ws;

  float* xd     = (float*)(ws + 0);          // 16,777,216 B
  float* meanx  = (float*)(ws + 16777216);   //     16,384 B
  float* meanxd = (float*)(ws + 16793600);   //     16,384 B
  u16*   q_ws   = (u16*)(ws + 16809984);     //  8,388,608 B  [b][n][p]
  u16*   kt_ws  = (u16*)(ws + 25198592);     //  2,097,152 B  [b][m][p]
  u16*   v_ws   = (u16*)(ws + 27295744);     //  8,388,608 B  [b][c][m]
  u16*   wq_b   = (u16*)(ws + 35684352);     //    131,072 B
  u16*   wk_b   = (u16*)(ws + 35815424);     //    131,072 B
  u16*   wv_b   = (u16*)(ws + 35946496);     //    524,288 B
  float* gc     = (float*)(ws + 36470784);   //     16,384 B

  prep_pool<<<dim3(B_ * C_), dim3(256), 0, stream>>>(x, xd, meanx, meanxd);
  f2bf3<<<dim3(1536), dim3(256), 0, stream>>>(wq, wk, wv, wq_b, wk_b, wv_b);
  // q = wq (x - meanx): [128x512]@[512x4096] -> q_ws[b][n][p]
  gemm_wx<true, true><<<dim3(64, 2, B_), dim3(256), 0, stream>>>(
      wq_b, x, meanx, q_ws, 128, 4096);
  // k = wk (xd - meanxd): -> kt_ws[b][m][p]
  gemm_wx<true, true><<<dim3(16, 2, B_), dim3(256), 0, stream>>>(
      wk_b, xd, meanxd, kt_ws, 128, 1024);
  // v = wv xd: -> v_ws[b][c][m]
  gemm_wx<false, false><<<dim3(16, 8, B_), dim3(256), 0, stream>>>(
      wv_b, xd, nullptr, v_ws, 512, 1024);
  mask_gc<<<dim3(B_), dim3(1024), 0, stream>>>(xd, v_ws, wm, bm, gc);
  attn<<<dim3(N_ / 16, B_), dim3(256), 0, stream>>>(q_ws, kt_ws, v_ws, gc, x,
                                                    gamma, out);
}

// Round 2
// 379.894 us; speedup vs baseline: 1.4369x; 1.4369x over previous
//
#include <hip/hip_runtime.h>

typedef float f32x4 __attribute__((ext_vector_type(4)));
typedef short bf16x8 __attribute__((ext_vector_type(8)));
typedef short s16x4 __attribute__((ext_vector_type(4)));
typedef unsigned short u16;

#define B_ 8
#define C_ 512
#define N_ 4096
#define M_ 1024
#define P_ 128
// 1 / (sqrt(128) * 0.05)
#define INV_ST 1.7677669529663689f
// exp2 form: p = exp2(S * log2e - M0 * log2e), M0 = 16
#define A2C 2.5506631384888954f     /* INV_ST * log2(e) */
#define B2C 23.083120654223414f    /* 16 * log2(e) */

__device__ __forceinline__ u16 f2b(float f) {
  unsigned u = __float_as_uint(f);
  u += 0x7fffu + ((u >> 16) & 1u);   // RNE; inputs finite
  return (u16)(u >> 16);
}
__device__ __forceinline__ float b2f(u16 h) {
  return __uint_as_float(((unsigned)h) << 16);
}
__device__ __forceinline__ float waveRedSum(float v) {
#pragma unroll
  for (int off = 32; off > 0; off >>= 1) v += __shfl_xor(v, off);
  return v;
}

// ---------------------------------------------------------------------------
// Kernel 1: per-(b,c) plane: maxpool 2x2 -> xd (fp32), spatial means of x, xd
// ---------------------------------------------------------------------------
__global__ __launch_bounds__(256) void prep_pool(const float* __restrict__ x,
                                                 float* __restrict__ xd,
                                                 float* __restrict__ meanx,
                                                 float* __restrict__ meanxd) {
  const int bc = blockIdx.x;          // 0..4095 = b*512 + c
  const int tid = threadIdx.x;
  const int lane = tid & 63, wid = tid >> 6;
  const float* xp = x + (size_t)bc * 4096;
  float* xdp = xd + (size_t)bc * 1024;
  __shared__ float xs[4096];
  __shared__ float w4[4], w4b[4];
  float s = 0.f;
#pragma unroll
  for (int i = 0; i < 16; ++i) {
    float v = xp[i * 256 + tid];
    xs[i * 256 + tid] = v;
    s += v;
  }
  s = waveRedSum(s);
  if (lane == 0) w4[wid] = s;
  __syncthreads();
  if (tid == 0) meanx[bc] = (w4[0] + w4[1] + w4[2] + w4[3]) * (1.f / 4096.f);
  float sd = 0.f;
#pragma unroll
  for (int i = 0; i < 4; ++i) {
    int mp = i * 256 + tid;               // pooled index 0..1023
    int r2 = mp >> 5, c2 = mp & 31;
    const float* p0 = xs + r2 * 128 + c2 * 2;
    float v = fmaxf(fmaxf(p0[0], p0[1]), fmaxf(p0[64], p0[65]));
    xdp[mp] = v;
    sd += v;
  }
  sd = waveRedSum(sd);
  if (lane == 0) w4b[wid] = sd;
  __syncthreads();
  if (tid == 0) meanxd[bc] = (w4b[0] + w4b[1] + w4b[2] + w4b[3]) * (1.f / 1024.f);
}

// ---------------------------------------------------------------------------
// Kernel 2: fp32 -> bf16 for wq (65536), wk (65536), wv (262144)
// ---------------------------------------------------------------------------
__global__ __launch_bounds__(256) void f2bf3(const float* __restrict__ a,
                                             const float* __restrict__ b,
                                             const float* __restrict__ c,
                                             u16* __restrict__ oa,
                                             u16* __restrict__ ob,
                                             u16* __restrict__ oc) {
  int i = blockIdx.x * 256 + threadIdx.x;
  if (i < 65536) oa[i] = f2b(a[i]);
  else if (i < 131072) ob[i - 65536] = f2b(b[i - 65536]);
  else if (i < 393216) oc[i - 131072] = f2b(c[i - 131072]);
}

// ---------------------------------------------------------------------------
// Kernel 3: GEMM  D[row=co][col=n] = sum_c A[co][c] * (B[b][c][n] - mean[b][c])
// A: bf16 [Cout][512].  B: fp32 [B][512][Ncols].  out bf16:
//   TRANS:  out[b][n][co]   (used for q: [b][n][p] and k^T: [b][m][p])
//   else :  out[b][co][n]   (used for v: [b][c][m])
// 64x64 tile, BK=64, 4 waves (2x2), LDS A[64][72] + B^T[64][72] (2-way max).
// ---------------------------------------------------------------------------
template <bool TRANS, bool SUBMEAN>
__global__ __launch_bounds__(256) void gemm_wx(const u16* __restrict__ A,
                                               const float* __restrict__ Bsrc,
                                               const float* __restrict__ mean,
                                               u16* __restrict__ outp,
                                               int Cout, int Ncols) {
  const int b = blockIdx.z;
  const int col0 = blockIdx.x * 64;
  const int row0 = blockIdx.y * 64;
  const int tid = threadIdx.x;
  const int lane = tid & 63, wid = tid >> 6;
  const int g = lane >> 4, c16 = lane & 15;
  const int wr = (wid >> 1) * 32, wc = (wid & 1) * 32;
  __shared__ __align__(16) u16 As[64][72];
  __shared__ __align__(16) u16 Bt[64][72];   // [col][k]
  const float* Bb = Bsrc + (size_t)b * 512 * Ncols;
  const float* mb = SUBMEAN ? (mean + b * 512) : nullptr;
  f32x4 acc[2][2];
#pragma unroll
  for (int i = 0; i < 2; ++i)
#pragma unroll
    for (int j = 0; j < 2; ++j) acc[i][j] = (f32x4){0.f, 0.f, 0.f, 0.f};

  for (int k0 = 0; k0 < 512; k0 += 64) {
    // stage A tile [64 rows][64 k]
#pragma unroll
    for (int i = 0; i < 2; ++i) {
      int f = tid + i * 256;
      int r = f >> 3, c8 = f & 7;
      *(bf16x8*)&As[r][c8 * 8] =
          *(const bf16x8*)(A + (size_t)(row0 + r) * 512 + k0 + c8 * 8);
    }
    // stage B tile [64 k][64 n] fp32 -> transposed bf16 Bt[n][k]
#pragma unroll
    for (int i = 0; i < 4; ++i) {
      int f = tid + i * 256;
      int kr = f >> 4, n4 = (f & 15) * 4;
      const float* src = Bb + (size_t)(k0 + kr) * Ncols + col0 + n4;
      float4 val = *(const float4*)src;
      if (SUBMEAN) {
        float mv = mb[k0 + kr];
        val.x -= mv; val.y -= mv; val.z -= mv; val.w -= mv;
      }
      Bt[n4 + 0][kr] = f2b(val.x);
      Bt[n4 + 1][kr] = f2b(val.y);
      Bt[n4 + 2][kr] = f2b(val.z);
      Bt[n4 + 3][kr] = f2b(val.w);
    }
    __syncthreads();
#pragma unroll
    for (int kk = 0; kk < 2; ++kk) {
      bf16x8 af[2], bfr[2];
#pragma unroll
      for (int i = 0; i < 2; ++i)
        af[i] = *(const bf16x8*)&As[wr + i * 16 + c16][kk * 32 + g * 8];
#pragma unroll
      for (int j = 0; j < 2; ++j)
        bfr[j] = *(const bf16x8*)&Bt[wc + j * 16 + c16][kk * 32 + g * 8];
#pragma unroll
      for (int i = 0; i < 2; ++i)
#pragma unroll
        for (int j = 0; j < 2; ++j)
          acc[i][j] = __builtin_amdgcn_mfma_f32_16x16x32_bf16(af[i], bfr[j],
                                                              acc[i][j], 0, 0, 0);
    }
    __syncthreads();
  }
  // epilogue; D lane mapping: row = +g*4+r, col = +c16
  if (TRANS) {
#pragma unroll
    for (int i = 0; i < 2; ++i)
#pragma unroll
      for (int j = 0; j < 2; ++j) {
        int row = row0 + wr + i * 16 + g * 4;
        int col = col0 + wc + j * 16 + c16;
        s16x4 h;
#pragma unroll
        for (int r = 0; r < 4; ++r) h[r] = (short)f2b(acc[i][j][r]);
        *(s16x4*)(outp + ((size_t)b * Ncols + col) * Cout + row) = h;
      }
  } else {
#pragma unroll
    for (int i = 0; i < 2; ++i)
#pragma unroll
      for (int j = 0; j < 2; ++j) {
        int row = row0 + wr + i * 16 + g * 4;
        int col = col0 + wc + j * 16 + c16;
#pragma unroll
        for (int r = 0; r < 4; ++r)
          outp[((size_t)b * Cout + row + r) * Ncols + col] = f2b(acc[i][j][r]);
      }
  }
}

// ---------------------------------------------------------------------------
// Kernel 4: global-context branch. One block (1024 thr) per batch.
// ---------------------------------------------------------------------------
__global__ __launch_bounds__(1024) void mask_gc(const float* __restrict__ xd,
                                                const u16* __restrict__ v,
                                                const float* __restrict__ wm,
                                                const float* __restrict__ bmp,
                                                float* __restrict__ gc) {
  const int b = blockIdx.x, tid = threadIdx.x;
  const int lane = tid & 63, wid = tid >> 6;
  __shared__ float ml[1024];
  __shared__ float r16[16];
  __shared__ float sred[2];
  const float* xb = xd + (size_t)b * (512 * 1024);
  float a0 = 0, a1 = 0, a2 = 0, a3 = 0;
  for (int c = 0; c < 512; c += 4) {
    a0 += wm[c + 0] * xb[(size_t)(c + 0) * 1024 + tid];
    a1 += wm[c + 1] * xb[(size_t)(c + 1) * 1024 + tid];
    a2 += wm[c + 2] * xb[(size_t)(c + 2) * 1024 + tid];
    a3 += wm[c + 3] * xb[(size_t)(c + 3) * 1024 + tid];
  }
  float logit = (a0 + a1) + (a2 + a3) + bmp[0];
  float mx = logit;
#pragma unroll
  for (int off = 32; off > 0; off >>= 1) mx = fmaxf(mx, __shfl_xor(mx, off));
  if (lane == 0) r16[wid] = mx;
  __syncthreads();
  if (tid == 0) {
    float m = r16[0];
    for (int i = 1; i < 16; ++i) m = fmaxf(m, r16[i]);
    sred[0] = m;
  }
  __syncthreads();
  float p = __expf(logit - sred[0]);
  float sm = waveRedSum(p);
  if (lane == 0) r16[wid] = sm;
  ml[tid] = p;
  __syncthreads();
  if (tid == 0) {
    float s2 = 0;
    for (int i = 0; i < 16; ++i) s2 += r16[i];
    sred[1] = 1.0f / s2;
  }
  __syncthreads();
  const float inv = sred[1];
  const int c = tid >> 1, half = tid & 1;
  const u16* vr = v + ((size_t)b * 512 + c) * 1024 + half * 512;
  const float* mlr = ml + half * 512;
  float s = 0;
  for (int i = 0; i < 64; ++i) {
    bf16x8 h = *(const bf16x8*)(vr + i * 8);
#pragma unroll
    for (int j = 0; j < 8; ++j) s += b2f((u16)h[j]) * mlr[i * 8 + j];
  }
  s += __shfl_xor(s, 1);
  if (half == 0) gc[b * 512 + c] = s * inv;
}

// ---------------------------------------------------------------------------
// Kernel 5: flash attention (fixed-shift softmax) + epilogue.
// Grid 512 flat: b = bid & 7 (batch<->XCD affinity), n0 = (bid>>3)*64.
// Block = 4 waves; QB=64 rows; m-loop 16 steps of 64; 2 barriers/step.
// S phase (swapped): wave w owns n rows w*16..+16. S^T = mfma(A=k[m], B=q[n])
//   -> D[row=m][col=n]: lane holds 16 m-values of row n = w*16+c16.
//   p = exp2(S*log2e - 16*log2e); l accumulated per-lane (register only).
// P -> LDS Pl[64 n][64 m] (stride 72: 2-way bank = free), packed b64 writes.
// PV phase: wave w owns c-slice w*128; A=v[c][m], B=Pl[n][m];
//   acc[8 cf][4 nb] f32x4 = 128 VGPR. D[row=c][col=n].
// Epilogue: out = gamma*acc/l + gc[c] + x.
// ---------------------------------------------------------------------------
__global__ __launch_bounds__(256, 2) void attn(const u16* __restrict__ q,
                                               const u16* __restrict__ kt,
                                               const u16* __restrict__ v,
                                               const float* __restrict__ gc,
                                               const float* __restrict__ x,
                                               const float* __restrict__ gamma,
                                               float* __restrict__ out) {
  const int bid = blockIdx.x;
  const int b = bid & 7;
  const int n0 = (bid >> 3) * 64;
  const int tid = threadIdx.x;
  const int lane = tid & 63, wid = tid >> 6;
  const int g = lane >> 4, c16 = lane & 15;
  __shared__ __align__(16) u16 Pl[64][72];
  __shared__ float l_s[64];

  // preload q fragments for this wave's 16 n-rows
  bf16x8 qf[4];
  const u16* qrow = q + ((size_t)b * N_ + n0 + wid * 16 + c16) * P_ + g * 8;
#pragma unroll
  for (int kf = 0; kf < 4; ++kf) qf[kf] = *(const bf16x8*)(qrow + kf * 32);

  f32x4 acc[8][4];
#pragma unroll
  for (int i = 0; i < 8; ++i)
#pragma unroll
    for (int j = 0; j < 4; ++j) acc[i][j] = (f32x4){0.f, 0.f, 0.f, 0.f};
  float lpart = 0.f;
  const int cs = wid * 128;
  const u16* ktb = kt + (size_t)b * M_ * P_;
  const u16* vb = v + ((size_t)b * C_ + cs + c16) * M_;

  for (int s = 0; s < 16; ++s) {
    const int m0 = s * 64;
    // ---- S^T tiles: 4 m-blocks of 16, k over 128 ----
    f32x4 sv[4];
#pragma unroll
    for (int mb = 0; mb < 4; ++mb) sv[mb] = (f32x4){0.f, 0.f, 0.f, 0.f};
#pragma unroll
    for (int mb = 0; mb < 4; ++mb) {
      const u16* krow = ktb + (size_t)(m0 + mb * 16 + c16) * P_ + g * 8;
#pragma unroll
      for (int kf = 0; kf < 4; ++kf) {
        bf16x8 kfr = *(const bf16x8*)(krow + kf * 32);
        sv[mb] = __builtin_amdgcn_mfma_f32_16x16x32_bf16(kfr, qf[kf], sv[mb], 0, 0, 0);
      }
    }
    // ---- exp, l-accumulate, pack, write P (row n = wid*16+c16) ----
    u16* prow = &Pl[wid * 16 + c16][0];
#pragma unroll
    for (int mb = 0; mb < 4; ++mb) {
      float p0 = exp2f(fmaf(sv[mb][0], A2C, -B2C));
      float p1 = exp2f(fmaf(sv[mb][1], A2C, -B2C));
      float p2 = exp2f(fmaf(sv[mb][2], A2C, -B2C));
      float p3 = exp2f(fmaf(sv[mb][3], A2C, -B2C));
      lpart += (p0 + p1) + (p2 + p3);
      uint2 pk;
      pk.x = (unsigned)f2b(p0) | ((unsigned)f2b(p1) << 16);
      pk.y = (unsigned)f2b(p2) | ((unsigned)f2b(p3) << 16);
      *(uint2*)(prow + mb * 16 + g * 4) = pk;
    }
    __syncthreads();                                    // B1: P visible
    // ---- PV: A = v rows (c), B = Pl rows (n) ----
#pragma unroll
    for (int kk = 0; kk < 2; ++kk) {
      bf16x8 pb[4];
#pragma unroll
      for (int nb = 0; nb < 4; ++nb)
        pb[nb] = *(const bf16x8*)&Pl[nb * 16 + c16][kk * 32 + g * 8];
      const u16* vk = vb + m0 + kk * 32 + g * 8;
#pragma unroll
      for (int cf = 0; cf < 8; ++cf) {
        bf16x8 va = *(const bf16x8*)(vk + (size_t)cf * 16 * M_);
#pragma unroll
        for (int nb = 0; nb < 4; ++nb)
          acc[cf][nb] = __builtin_amdgcn_mfma_f32_16x16x32_bf16(va, pb[nb],
                                                                acc[cf][nb], 0, 0, 0);
      }
    }
    __syncthreads();                                    // B2: Pl consumed
  }

  // ---- l: reduce over g-lanes, exchange across waves ----
  lpart += __shfl_xor(lpart, 16);
  lpart += __shfl_xor(lpart, 32);
  if (lane < 16) l_s[wid * 16 + lane] = lpart;
  __syncthreads();
  float linv[4];
#pragma unroll
  for (int nb = 0; nb < 4; ++nb) linv[nb] = 1.0f / l_s[nb * 16 + c16];
  const float gam = gamma[0];
  // ---- epilogue: out[b][c][n] = gam*acc/l + gc + x ----
#pragma unroll
  for (int cf = 0; cf < 8; ++cf) {
    const int c = cs + cf * 16 + g * 4;
    float gcv[4];
#pragma unroll
    for (int r = 0; r < 4; ++r) gcv[r] = gc[b * C_ + c + r];
#pragma unroll
    for (int nb = 0; nb < 4; ++nb) {
      const size_t idx0 = ((size_t)b * C_ + c) * (size_t)N_ + n0 + nb * 16 + c16;
#pragma unroll
      for (int r = 0; r < 4; ++r) {
        const size_t idx = idx0 + (size_t)r * N_;
        out[idx] = gam * acc[cf][nb][r] * linv[nb] + gcv[r] + x[idx];
      }
    }
  }
}

// ---------------------------------------------------------------------------
extern "C" void kernel_launch(void* const* d_in, const int* in_sizes, int n_in,
                              void* d_out, int out_size, void* d_ws, size_t ws_size,
                              hipStream_t stream) {
  const float* x     = (const float*)d_in[0];
  const float* wq    = (const float*)d_in[1];
  const float* wk    = (const float*)d_in[3];
  const float* wv    = (const float*)d_in[5];
  const float* wm    = (const float*)d_in[6];
  const float* bm    = (const float*)d_in[7];
  const float* gamma = (const float*)d_in[8];
  float* out = (float*)d_out;
  char* ws = (char*)d_ws;

  float* xd     = (float*)(ws + 0);          // 16,777,216 B
  float* meanx  = (float*)(ws + 16777216);   //     16,384 B
  float* meanxd = (float*)(ws + 16793600);   //     16,384 B
  u16*   q_ws   = (u16*)(ws + 16809984);     //  8,388,608 B  [b][n][p]
  u16*   kt_ws  = (u16*)(ws + 25198592);     //  2,097,152 B  [b][m][p]
  u16*   v_ws   = (u16*)(ws + 27295744);     //  8,388,608 B  [b][c][m]
  u16*   wq_b   = (u16*)(ws + 35684352);     //    131,072 B
  u16*   wk_b   = (u16*)(ws + 35815424);     //    131,072 B
  u16*   wv_b   = (u16*)(ws + 35946496);     //    524,288 B
  float* gc     = (float*)(ws + 36470784);   //     16,384 B

  prep_pool<<<dim3(B_ * C_), dim3(256), 0, stream>>>(x, xd, meanx, meanxd);
  f2bf3<<<dim3(1536), dim3(256), 0, stream>>>(wq, wk, wv, wq_b, wk_b, wv_b);
  gemm_wx<true, true><<<dim3(64, 2, B_), dim3(256), 0, stream>>>(
      wq_b, x, meanx, q_ws, 128, 4096);
  gemm_wx<true, true><<<dim3(16, 2, B_), dim3(256), 0, stream>>>(
      wk_b, xd, meanxd, kt_ws, 128, 1024);
  gemm_wx<false, false><<<dim3(16, 8, B_), dim3(256), 0, stream>>>(
      wv_b, xd, nullptr, v_ws, 512, 1024);
  mask_gc<<<dim3(B_), dim3(1024), 0, stream>>>(xd, v_ws, wm, bm, gc);
  attn<<<dim3(512), dim3(256), 0, stream>>>(q_ws, kt_ws, v_ws, gc, x, gamma, out);
}

// Round 3
// 307.243 us; speedup vs baseline: 1.7766x; 1.2365x over previous
//
#include <hip/hip_runtime.h>

typedef float f32x4 __attribute__((ext_vector_type(4)));
typedef short bf16x8 __attribute__((ext_vector_type(8)));
typedef short s16x4 __attribute__((ext_vector_type(4)));
typedef unsigned short u16;

#define B_ 8
#define C_ 512
#define N_ 4096
#define M_ 1024
#define P_ 128
// 1 / (sqrt(128) * 0.05)
#define INV_ST 1.7677669529663689f
// fixed-shift softmax: p = exp2(S*INV_ST*log2e - 16*log2e)
#define A2C 2.5506631384888954f
#define B2C 23.083120654223414f

#define MFMA __builtin_amdgcn_mfma_f32_16x16x32_bf16

__device__ __forceinline__ u16 f2b(float f) {
  unsigned u = __float_as_uint(f);
  u += 0x7fffu + ((u >> 16) & 1u);   // RNE; inputs finite
  return (u16)(u >> 16);
}
__device__ __forceinline__ float b2f(u16 h) {
  return __uint_as_float(((unsigned)h) << 16);
}
__device__ __forceinline__ float waveRedSum(float v) {
#pragma unroll
  for (int off = 32; off > 0; off >>= 1) v += __shfl_xor(v, off);
  return v;
}
__device__ __forceinline__ void gload_lds16(const u16* g, u16* l) {
  __builtin_amdgcn_global_load_lds(
      (const __attribute__((address_space(1))) void*)g,
      (__attribute__((address_space(3))) void*)l, 16, 0, 0);
}

// ---------------------------------------------------------------------------
// Kernel 1: per-(b,c) plane: maxpool 2x2 -> xd (fp32), spatial means of x, xd
// ---------------------------------------------------------------------------
__global__ __launch_bounds__(256) void prep_pool(const float* __restrict__ x,
                                                 float* __restrict__ xd,
                                                 float* __restrict__ meanx,
                                                 float* __restrict__ meanxd) {
  const int bc = blockIdx.x;
  const int tid = threadIdx.x;
  const int lane = tid & 63, wid = tid >> 6;
  const float* xp = x + (size_t)bc * 4096;
  float* xdp = xd + (size_t)bc * 1024;
  __shared__ float xs[4096];
  __shared__ float w4[4], w4b[4];
  float s = 0.f;
#pragma unroll
  for (int i = 0; i < 16; ++i) {
    float v = xp[i * 256 + tid];
    xs[i * 256 + tid] = v;
    s += v;
  }
  s = waveRedSum(s);
  if (lane == 0) w4[wid] = s;
  __syncthreads();
  if (tid == 0) meanx[bc] = (w4[0] + w4[1] + w4[2] + w4[3]) * (1.f / 4096.f);
  float sd = 0.f;
#pragma unroll
  for (int i = 0; i < 4; ++i) {
    int mp = i * 256 + tid;
    int r2 = mp >> 5, c2 = mp & 31;
    const float* p0 = xs + r2 * 128 + c2 * 2;
    float v = fmaxf(fmaxf(p0[0], p0[1]), fmaxf(p0[64], p0[65]));
    xdp[mp] = v;
    sd += v;
  }
  sd = waveRedSum(sd);
  if (lane == 0) w4b[wid] = sd;
  __syncthreads();
  if (tid == 0) meanxd[bc] = (w4b[0] + w4b[1] + w4b[2] + w4b[3]) * (1.f / 1024.f);
}

// ---------------------------------------------------------------------------
// Kernel 2: fp32 -> bf16 for wq, wk, wv
// ---------------------------------------------------------------------------
__global__ __launch_bounds__(256) void f2bf3(const float* __restrict__ a,
                                             const float* __restrict__ b,
                                             const float* __restrict__ c,
                                             u16* __restrict__ oa,
                                             u16* __restrict__ ob,
                                             u16* __restrict__ oc) {
  int i = blockIdx.x * 256 + threadIdx.x;
  if (i < 65536) oa[i] = f2b(a[i]);
  else if (i < 131072) ob[i - 65536] = f2b(b[i - 65536]);
  else if (i < 393216) oc[i - 131072] = f2b(c[i - 131072]);
}

// ---------------------------------------------------------------------------
// Kernel 3: GEMM (ROWS x 64 tile, BK=64, 4 waves 2x2)
// ---------------------------------------------------------------------------
template <int ROWS, bool TRANS, bool SUBMEAN>
__global__ __launch_bounds__(256) void gemm_wx(const u16* __restrict__ A,
                                               const float* __restrict__ Bsrc,
                                               const float* __restrict__ mean,
                                               u16* __restrict__ outp,
                                               int Cout, int Ncols) {
  constexpr int IT = ROWS / 32;   // 16-row subtiles per wave
  const int b = blockIdx.z;
  const int col0 = blockIdx.x * 64;
  const int row0 = blockIdx.y * ROWS;
  const int tid = threadIdx.x;
  const int lane = tid & 63, wid = tid >> 6;
  const int g = lane >> 4, c16 = lane & 15;
  const int wr = (wid >> 1) * (ROWS / 2), wc = (wid & 1) * 32;
  __shared__ __align__(16) u16 As[ROWS][72];
  __shared__ __align__(16) u16 Bt[64][72];
  const float* Bb = Bsrc + (size_t)b * 512 * Ncols;
  const float* mb = SUBMEAN ? (mean + b * 512) : nullptr;
  f32x4 acc[IT][2];
#pragma unroll
  for (int i = 0; i < IT; ++i)
#pragma unroll
    for (int j = 0; j < 2; ++j) acc[i][j] = (f32x4){0.f, 0.f, 0.f, 0.f};

  for (int k0 = 0; k0 < 512; k0 += 64) {
#pragma unroll
    for (int i = 0; i < IT; ++i) {
      int f = tid + i * 256;
      int r = f >> 3, c8 = f & 7;
      *(bf16x8*)&As[r][c8 * 8] =
          *(const bf16x8*)(A + (size_t)(row0 + r) * 512 + k0 + c8 * 8);
    }
#pragma unroll
    for (int i = 0; i < 4; ++i) {
      int f = tid + i * 256;
      int kr = f >> 4, n4 = (f & 15) * 4;
      const float* src = Bb + (size_t)(k0 + kr) * Ncols + col0 + n4;
      float4 val = *(const float4*)src;
      if (SUBMEAN) {
        float mv = mb[k0 + kr];
        val.x -= mv; val.y -= mv; val.z -= mv; val.w -= mv;
      }
      Bt[n4 + 0][kr] = f2b(val.x);
      Bt[n4 + 1][kr] = f2b(val.y);
      Bt[n4 + 2][kr] = f2b(val.z);
      Bt[n4 + 3][kr] = f2b(val.w);
    }
    __syncthreads();
#pragma unroll
    for (int kk = 0; kk < 2; ++kk) {
      bf16x8 bfr[2];
#pragma unroll
      for (int j = 0; j < 2; ++j)
        bfr[j] = *(const bf16x8*)&Bt[wc + j * 16 + c16][kk * 32 + g * 8];
#pragma unroll
      for (int i = 0; i < IT; ++i) {
        bf16x8 af = *(const bf16x8*)&As[wr + i * 16 + c16][kk * 32 + g * 8];
#pragma unroll
        for (int j = 0; j < 2; ++j)
          acc[i][j] = MFMA(af, bfr[j], acc[i][j], 0, 0, 0);
      }
    }
    __syncthreads();
  }
  if (TRANS) {
#pragma unroll
    for (int i = 0; i < IT; ++i)
#pragma unroll
      for (int j = 0; j < 2; ++j) {
        int row = row0 + wr + i * 16 + g * 4;
        int col = col0 + wc + j * 16 + c16;
        s16x4 h;
#pragma unroll
        for (int r = 0; r < 4; ++r) h[r] = (short)f2b(acc[i][j][r]);
        *(s16x4*)(outp + ((size_t)b * Ncols + col) * Cout + row) = h;
      }
  } else {
#pragma unroll
    for (int i = 0; i < IT; ++i)
#pragma unroll
      for (int j = 0; j < 2; ++j) {
        int row = row0 + wr + i * 16 + g * 4;
        int col = col0 + wc + j * 16 + c16;
#pragma unroll
        for (int r = 0; r < 4; ++r)
          outp[((size_t)b * Cout + row + r) * Ncols + col] = f2b(acc[i][j][r]);
      }
  }
}

// ---------------------------------------------------------------------------
// Kernel 4a: logits[b][m] = sum_c wm[c]*xd[b][c][m] + bm
// grid: 8 b x 32 m-chunks = 256 blocks, 128 threads (c-split 4)
// ---------------------------------------------------------------------------
__global__ __launch_bounds__(128) void k_logits(const float* __restrict__ xd,
                                                const float* __restrict__ wm,
                                                const float* __restrict__ bmp,
                                                float* __restrict__ logits) {
  const int b = blockIdx.x >> 5, mc = blockIdx.x & 31;
  const int t = threadIdx.x;
  const int ml = t & 31, cq = t >> 5;
  const int m = mc * 32 + ml;
  __shared__ float part[4][32];
  const float* xb = xd + (size_t)b * 512 * 1024 + m;
  float s0 = 0, s1 = 0, s2 = 0, s3 = 0;
  const int cb = cq * 128;
#pragma unroll 8
  for (int c = 0; c < 128; c += 4) {
    s0 += wm[cb + c + 0] * xb[(size_t)(cb + c + 0) * 1024];
    s1 += wm[cb + c + 1] * xb[(size_t)(cb + c + 1) * 1024];
    s2 += wm[cb + c + 2] * xb[(size_t)(cb + c + 2) * 1024];
    s3 += wm[cb + c + 3] * xb[(size_t)(cb + c + 3) * 1024];
  }
  part[cq][ml] = (s0 + s1) + (s2 + s3);
  __syncthreads();
  if (t < 32)
    logits[b * 1024 + mc * 32 + t] =
        part[0][t] + part[1][t] + part[2][t] + part[3][t] + bmp[0];
}

// ---------------------------------------------------------------------------
// Kernel 4b: softmax(logits) (redundant per block, tiny) + gc[b][c] = v . p
// grid: 8 b x 16 c-chunks = 128 blocks, 256 threads
// ---------------------------------------------------------------------------
__global__ __launch_bounds__(256) void k_gc(const float* __restrict__ logits,
                                            const u16* __restrict__ v,
                                            float* __restrict__ gc) {
  const int b = blockIdx.x >> 4, cc = blockIdx.x & 15;
  const int tid = threadIdx.x;
  const int lane = tid & 63, wid = tid >> 6;
  __shared__ float pl[1024];
  __shared__ float r4[4];
  __shared__ float stot[2];
  float4 lv = *(const float4*)&logits[b * 1024 + tid * 4];
  float mx = fmaxf(fmaxf(lv.x, lv.y), fmaxf(lv.z, lv.w));
#pragma unroll
  for (int off = 32; off > 0; off >>= 1) mx = fmaxf(mx, __shfl_xor(mx, off));
  if (lane == 0) r4[wid] = mx;
  __syncthreads();
  if (tid == 0) stot[0] = fmaxf(fmaxf(r4[0], r4[1]), fmaxf(r4[2], r4[3]));
  __syncthreads();
  const float M = stot[0];
  float e0 = __expf(lv.x - M), e1 = __expf(lv.y - M);
  float e2 = __expf(lv.z - M), e3 = __expf(lv.w - M);
  pl[tid * 4 + 0] = e0; pl[tid * 4 + 1] = e1;
  pl[tid * 4 + 2] = e2; pl[tid * 4 + 3] = e3;
  float ps = waveRedSum((e0 + e1) + (e2 + e3));
  if (lane == 0) r4[wid] = ps;
  __syncthreads();
  if (tid == 0) stot[1] = 1.0f / (r4[0] + r4[1] + r4[2] + r4[3]);
  __syncthreads();
  const float inv = stot[1];
  const int c = cc * 32 + (tid >> 3), sub = tid & 7;
  const u16* vr = v + ((size_t)b * 512 + c) * 1024 + sub * 128;
  const float* plr = pl + sub * 128;
  float s = 0;
#pragma unroll
  for (int i = 0; i < 16; ++i) {
    bf16x8 h = *(const bf16x8*)(vr + i * 8);
#pragma unroll
    for (int j = 0; j < 8; ++j) s += b2f((u16)h[j]) * plr[i * 8 + j];
  }
  s += __shfl_xor(s, 1);
  s += __shfl_xor(s, 2);
  s += __shfl_xor(s, 4);
  if (sub == 0) gc[b * 512 + c] = s * inv;
}

// ---------------------------------------------------------------------------
// Kernel 5: flash attention, 2-phase pipelined (T3-lite), fixed-shift softmax.
// 512 thr = 8 waves; QB=64; grid 512: b=bid&7 (XCD affinity), n0=(bid>>3)*64.
// wave wid: mb=wid&3 (m-16-slice for S), nh=wid>>2 (n-32-half for S);
//           PV c-slice = wid*64.
// LDS (dynamic 140288B): Vl[2][512c][64m] xor-swizzled (T2, via pre-swizzled
// global source for global_load_lds, m173); Pl[64n][64m] xor-swizzled; l_s.
// Pipeline per step: S(s) [K regs] -> B1 -> issue K(s+1)+stageV(s+1), write
// P(s) -> s_waitcnt vmcnt(12) lgkmcnt(0) -> B2 (raw) -> PV(s) from LDS.
// Counted vmcnt keeps the 12 next-step loads in flight across B2 (T4).
// ---------------------------------------------------------------------------
__global__ __launch_bounds__(512, 2) void attn(const u16* __restrict__ q,
                                               const u16* __restrict__ kt,
                                               const u16* __restrict__ v,
                                               const float* __restrict__ gc,
                                               const float* __restrict__ x,
                                               const float* __restrict__ gamma,
                                               float* __restrict__ out) {
  extern __shared__ __align__(16) char smem[];
  u16* Vl = (u16*)smem;                   // 2 x 32768 halves (128 KB)
  u16* Pl = (u16*)(smem + 131072);        // 64 x 64 halves (8 KB)
  float* l_s = (float*)(smem + 139264);   // 4 x 64 (1 KB)

  const int bid = blockIdx.x;
  const int b = bid & 7;
  const int n0 = (bid >> 3) * 64;
  const int tid = threadIdx.x;
  const int lane = tid & 63, wid = tid >> 6;
  const int g = lane >> 4, c16 = lane & 15;
  const int mb = wid & 3, nh = wid >> 2;
  const int xsw = (c16 & 7) << 3;         // swizzle in half-units

  // Q fragments (2 n-tiles)
  bf16x8 qf[2][4];
  {
    const u16* qr = q + ((size_t)b * N_ + n0 + nh * 32 + c16) * P_ + g * 8;
#pragma unroll
    for (int t = 0; t < 2; ++t)
#pragma unroll
      for (int kf = 0; kf < 4; ++kf)
        qf[t][kf] = *(const bf16x8*)(qr + t * 16 * P_ + kf * 32);
  }
  const u16* ktr = kt + ((size_t)b * M_ + mb * 16 + c16) * P_ + g * 8;
  // prologue: K(0) regs, stage V(0)
  bf16x8 kb[2][4];
#pragma unroll
  for (int kf = 0; kf < 4; ++kf) kb[0][kf] = *(const bf16x8*)(ktr + kf * 32);
  const u16* vst = v + ((size_t)b * C_ + wid * 64 + (lane >> 3)) * M_ +
                   ((lane & 7) ^ (lane >> 3)) * 8;
#pragma unroll
  for (int i = 0; i < 8; ++i)
    gload_lds16(vst + (size_t)i * 8 * M_, Vl + (wid * 8 + i) * 512);

  f32x4 acc[4][4];   // [cf][nb]
#pragma unroll
  for (int i = 0; i < 4; ++i)
#pragma unroll
    for (int j = 0; j < 4; ++j) acc[i][j] = (f32x4){0.f, 0.f, 0.f, 0.f};
  float lp0 = 0.f, lp1 = 0.f;

#pragma unroll
  for (int s = 0; s < 16; ++s) {
    const int par = s & 1, nxt = par ^ 1;
    const int m0n = ((s + 1) & 15) * 64;   // wraps at s=15: harmless re-load
    // ---- S(s): 8 MFMA from registers ----
    f32x4 sv0 = (f32x4){0.f, 0.f, 0.f, 0.f};
    f32x4 sv1 = (f32x4){0.f, 0.f, 0.f, 0.f};
#pragma unroll
    for (int kf = 0; kf < 4; ++kf) {
      sv0 = MFMA(kb[par][kf], qf[0][kf], sv0, 0, 0, 0);
      sv1 = MFMA(kb[par][kf], qf[1][kf], sv1, 0, 0, 0);
    }
    // exp + l-accumulate + pack
    float p00 = exp2f(fmaf(sv0[0], A2C, -B2C));
    float p01 = exp2f(fmaf(sv0[1], A2C, -B2C));
    float p02 = exp2f(fmaf(sv0[2], A2C, -B2C));
    float p03 = exp2f(fmaf(sv0[3], A2C, -B2C));
    float p10 = exp2f(fmaf(sv1[0], A2C, -B2C));
    float p11 = exp2f(fmaf(sv1[1], A2C, -B2C));
    float p12 = exp2f(fmaf(sv1[2], A2C, -B2C));
    float p13 = exp2f(fmaf(sv1[3], A2C, -B2C));
    lp0 += (p00 + p01) + (p02 + p03);
    lp1 += (p10 + p11) + (p12 + p13);
    uint2 w0, w1;
    w0.x = (unsigned)f2b(p00) | ((unsigned)f2b(p01) << 16);
    w0.y = (unsigned)f2b(p02) | ((unsigned)f2b(p03) << 16);
    w1.x = (unsigned)f2b(p10) | ((unsigned)f2b(p11) << 16);
    w1.y = (unsigned)f2b(p12) | ((unsigned)f2b(p13) << 16);

    __builtin_amdgcn_sched_barrier(0);
    __builtin_amdgcn_s_barrier();                       // B1
    __builtin_amdgcn_sched_barrier(0);
    // issue K(s+1) (4 loads, older) then stage V(s+1) (8 gload_lds, newer)
#pragma unroll
    for (int kf = 0; kf < 4; ++kf)
      kb[nxt][kf] = *(const bf16x8*)(ktr + (size_t)m0n * P_ + kf * 32);
#pragma unroll
    for (int i = 0; i < 8; ++i)
      gload_lds16(vst + (size_t)(m0n + i * 8 * M_),
                  Vl + nxt * 32768 + (wid * 8 + i) * 512);
    // write P(s) (xor-swizzled rows)
    {
      const int nA = nh * 32 + c16;
      const int o = (mb * 16 + g * 4) ^ xsw;
      *(uint2*)&Pl[nA * 64 + o] = w0;
      *(uint2*)&Pl[(nA + 16) * 64 + o] = w1;
    }
    asm volatile("s_waitcnt vmcnt(12) lgkmcnt(0)" ::: "memory");
    __builtin_amdgcn_sched_barrier(0);
    __builtin_amdgcn_s_barrier();                       // B2
    __builtin_amdgcn_sched_barrier(0);
    // ---- PV(s): V,P from LDS ----
    const u16* VlP = Vl + par * 32768;
#pragma unroll
    for (int kk = 0; kk < 2; ++kk) {
      bf16x8 pb[4];
#pragma unroll
      for (int nb = 0; nb < 4; ++nb)
        pb[nb] = *(const bf16x8*)&Pl[(nb * 16 + c16) * 64 + ((kk * 32 + g * 8) ^ xsw)];
#pragma unroll
      for (int cf = 0; cf < 4; ++cf) {
        bf16x8 va = *(const bf16x8*)&VlP[(wid * 64 + cf * 16 + c16) * 64 +
                                         ((kk * 32 + g * 8) ^ xsw)];
#pragma unroll
        for (int nb = 0; nb < 4; ++nb)
          acc[cf][nb] = MFMA(va, pb[nb], acc[cf][nb], 0, 0, 0);
      }
    }
  }

  // ---- l reduction: over g (shfl), then across mb via LDS ----
  lp0 += __shfl_xor(lp0, 16); lp0 += __shfl_xor(lp0, 32);
  lp1 += __shfl_xor(lp1, 16); lp1 += __shfl_xor(lp1, 32);
  if (lane < 16) {
    l_s[mb * 64 + nh * 32 + lane] = lp0;
    l_s[mb * 64 + nh * 32 + 16 + lane] = lp1;
  }
  __syncthreads();
  float linv[4];
#pragma unroll
  for (int nb = 0; nb < 4; ++nb) {
    int n = nb * 16 + c16;
    linv[nb] = 1.0f / (l_s[n] + l_s[64 + n] + l_s[128 + n] + l_s[192 + n]);
  }
  const float gam = gamma[0];
#pragma unroll
  for (int cf = 0; cf < 4; ++cf) {
    const int c = wid * 64 + cf * 16 + g * 4;
    float gcv[4];
#pragma unroll
    for (int r = 0; r < 4; ++r) gcv[r] = gc[b * C_ + c + r];
#pragma unroll
    for (int nb = 0; nb < 4; ++nb) {
      const size_t idx0 = ((size_t)b * C_ + c) * (size_t)N_ + n0 + nb * 16 + c16;
#pragma unroll
      for (int r = 0; r < 4; ++r) {
        const size_t idx = idx0 + (size_t)r * N_;
        out[idx] = gam * acc[cf][nb][r] * linv[nb] + gcv[r] + x[idx];
      }
    }
  }
}

// ---------------------------------------------------------------------------
extern "C" void kernel_launch(void* const* d_in, const int* in_sizes, int n_in,
                              void* d_out, int out_size, void* d_ws, size_t ws_size,
                              hipStream_t stream) {
  const float* x     = (const float*)d_in[0];
  const float* wq    = (const float*)d_in[1];
  const float* wk    = (const float*)d_in[3];
  const float* wv    = (const float*)d_in[5];
  const float* wm    = (const float*)d_in[6];
  const float* bm    = (const float*)d_in[7];
  const float* gamma = (const float*)d_in[8];
  float* out = (float*)d_out;
  char* ws = (char*)d_ws;

  float* xd     = (float*)(ws + 0);          // 16,777,216 B
  float* meanx  = (float*)(ws + 16777216);
  float* meanxd = (float*)(ws + 16793600);
  u16*   q_ws   = (u16*)(ws + 16809984);     // [b][n][p]
  u16*   kt_ws  = (u16*)(ws + 25198592);     // [b][m][p]
  u16*   v_ws   = (u16*)(ws + 27295744);     // [b][c][m]
  u16*   wq_b   = (u16*)(ws + 35684352);
  u16*   wk_b   = (u16*)(ws + 35815424);
  u16*   wv_b   = (u16*)(ws + 35946496);
  float* gc     = (float*)(ws + 36470784);
  float* logits = (float*)(ws + 36487168);   // 32,768 B

  prep_pool<<<dim3(B_ * C_), dim3(256), 0, stream>>>(x, xd, meanx, meanxd);
  f2bf3<<<dim3(1536), dim3(256), 0, stream>>>(wq, wk, wv, wq_b, wk_b, wv_b);
  gemm_wx<128, true, true><<<dim3(64, 1, B_), dim3(256), 0, stream>>>(
      wq_b, x, meanx, q_ws, 128, 4096);
  gemm_wx<128, true, true><<<dim3(16, 1, B_), dim3(256), 0, stream>>>(
      wk_b, xd, meanxd, kt_ws, 128, 1024);
  gemm_wx<128, false, false><<<dim3(16, 4, B_), dim3(256), 0, stream>>>(
      wv_b, xd, nullptr, v_ws, 512, 1024);
  k_logits<<<dim3(256), dim3(128), 0, stream>>>(xd, wm, bm, logits);
  k_gc<<<dim3(128), dim3(256), 0, stream>>>(logits, v_ws, gc);

  hipFuncSetAttribute((const void*)attn,
                      hipFuncAttributeMaxDynamicSharedMemorySize, 140288);
  attn<<<dim3(512), dim3(512), 140288, stream>>>(q_ws, kt_ws, v_ws, gc, x,
                                                 gamma, out);
}

// Round 4
// 255.181 us; speedup vs baseline: 2.1391x; 1.2040x over previous
//
#include <hip/hip_runtime.h>

typedef float f32x4 __attribute__((ext_vector_type(4)));
typedef short bf16x8 __attribute__((ext_vector_type(8)));
typedef short s16x4 __attribute__((ext_vector_type(4)));
typedef unsigned short u16;

#define B_ 8
#define C_ 512
#define N_ 4096
#define M_ 1024
#define P_ 128
// fixed-shift softmax: p = exp2(S*(1/(sqrt(128)*0.05))*log2e - 16*log2e)
#define A2C 2.5506631384888954f
#define B2C 23.083120654223414f

#define MFMA __builtin_amdgcn_mfma_f32_16x16x32_bf16

__device__ __forceinline__ u16 f2b(float f) {
  unsigned u = __float_as_uint(f);
  u += 0x7fffu + ((u >> 16) & 1u);   // RNE; inputs finite
  return (u16)(u >> 16);
}
__device__ __forceinline__ float b2f(u16 h) {
  return __uint_as_float(((unsigned)h) << 16);
}
__device__ __forceinline__ float waveRedSum(float v) {
#pragma unroll
  for (int off = 32; off > 0; off >>= 1) v += __shfl_xor(v, off);
  return v;
}
__device__ __forceinline__ void gload_lds16(const u16* g, u16* l) {
  __builtin_amdgcn_global_load_lds(
      (const __attribute__((address_space(1))) void*)g,
      (__attribute__((address_space(3))) void*)l, 16, 0, 0);
}

// ---------------------------------------------------------------------------
// Kernel 1: tile-transpose x -> xt bf16 [b][n][c]; 2x2 maxpool -> xdt bf16
// [b][m][c]; spatial means of x, xd via block-reduced atomics.
// grid: b(8) x ctile(8) x hpair(32) = 2048 blocks, 256 thr.
// ---------------------------------------------------------------------------
__global__ __launch_bounds__(256) void prep_tx(const float* __restrict__ x,
                                               u16* __restrict__ xt,
                                               u16* __restrict__ xdt,
                                               float* __restrict__ meanx,
                                               float* __restrict__ meanxd) {
  const int bid = blockIdx.x;
  const int b = bid >> 8, ct = (bid >> 5) & 7, hp = bid & 31;
  const int t = threadIdx.x;
  const int lane = t & 63, wid = t >> 6;
  __shared__ float xs[64 * 133];
  __shared__ float part[4][64];
  const float* xb = x + ((size_t)(b * 512 + ct * 64) * 4096) + hp * 128;
  // load 64c x 128n tile (coalesced along n)
#pragma unroll
  for (int it = 0; it < 32; ++it) {
    int c = it * 2 + (t >> 7);
    int n = t & 127;
    xs[c * 133 + n] = xb[(size_t)c * 4096 + n];
  }
  __syncthreads();
  // meanx partials: c = t>>2, quarter q = t&3
  {
    int c = t >> 2, qq = t & 3;
    float s = 0;
#pragma unroll
    for (int j = 0; j < 32; ++j) s += xs[c * 133 + qq * 32 + j];
    s += __shfl_xor(s, 1);
    s += __shfl_xor(s, 2);
    if (qq == 0) atomicAdd(&meanx[b * 512 + ct * 64 + c], s * (1.f / 4096.f));
  }
  // xt[b][n][c] writes (2 c per lane packed u32)
#pragma unroll
  for (int it = 0; it < 16; ++it) {
    int n = it * 8 + (t >> 5), cp = t & 31;
    float lo = xs[(2 * cp) * 133 + n], hi = xs[(2 * cp + 1) * 133 + n];
    unsigned u = (unsigned)f2b(lo) | ((unsigned)f2b(hi) << 16);
    *(unsigned*)(xt + (((size_t)b * 4096) + hp * 128 + n) * 512 + ct * 64 + 2 * cp) = u;
  }
  // pool 2x2 -> xdt[b][m][c] + meanxd partials
  float s0 = 0, s1 = 0;
  const int cp = t & 31;
#pragma unroll
  for (int it = 0; it < 4; ++it) {
    int wm = it * 8 + (t >> 5);
    int c0 = 2 * cp;
    float a = fmaxf(fmaxf(xs[c0 * 133 + 2 * wm], xs[c0 * 133 + 2 * wm + 1]),
                    fmaxf(xs[c0 * 133 + 64 + 2 * wm], xs[c0 * 133 + 64 + 2 * wm + 1]));
    float d = fmaxf(fmaxf(xs[(c0 + 1) * 133 + 2 * wm], xs[(c0 + 1) * 133 + 2 * wm + 1]),
                    fmaxf(xs[(c0 + 1) * 133 + 64 + 2 * wm], xs[(c0 + 1) * 133 + 64 + 2 * wm + 1]));
    unsigned u = (unsigned)f2b(a) | ((unsigned)f2b(d) << 16);
    *(unsigned*)(xdt + (((size_t)b * 1024) + hp * 32 + wm) * 512 + ct * 64 + c0) = u;
    s0 += a; s1 += d;
  }
  s0 += __shfl_xor(s0, 32);
  s1 += __shfl_xor(s1, 32);
  if (lane < 32) { part[wid][2 * cp] = s0; part[wid][2 * cp + 1] = s1; }
  __syncthreads();
  if (t < 64)
    atomicAdd(&meanxd[b * 512 + ct * 64 + t],
              (part[0][t] + part[1][t] + part[2][t] + part[3][t]) * (1.f / 1024.f));
}

// ---------------------------------------------------------------------------
// Kernel 2 (fused): weight f2b casts | corr vectors | mask logits.
// blocks 0..1535: wq/wk/wv -> bf16. 1536..1551: corr_q/corr_k[b][p] = w.mean.
// 1552..3599: logits[b][m] = wm . xdt[b][m][:] + bm (1 wave per m).
// ---------------------------------------------------------------------------
__global__ __launch_bounds__(256) void wcvt(const float* __restrict__ wq,
                                            const float* __restrict__ wk,
                                            const float* __restrict__ wv,
                                            const float* __restrict__ wm,
                                            const float* __restrict__ bm,
                                            const float* __restrict__ meanx,
                                            const float* __restrict__ meanxd,
                                            const u16* __restrict__ xdt,
                                            u16* __restrict__ wq_b,
                                            u16* __restrict__ wk_b,
                                            u16* __restrict__ wv_b,
                                            float* __restrict__ corr_q,
                                            float* __restrict__ corr_k,
                                            float* __restrict__ logits) {
  const int bid = blockIdx.x, t = threadIdx.x;
  if (bid < 1536) {
    int i = bid * 256 + t;
    if (i < 65536) wq_b[i] = f2b(wq[i]);
    else if (i < 131072) wk_b[i - 65536] = f2b(wk[i - 65536]);
    else wv_b[i - 131072] = f2b(wv[i - 131072]);
  } else if (bid < 1552) {
    int blk = bid - 1536, b = blk & 7, sel = blk >> 3;
    const float* w = sel ? wk : wq;
    const float* mn = (sel ? meanxd : meanx) + b * 512;
    int p = t >> 1, h = t & 1;
    const float* wr = w + p * 512 + h * 256;
    const float* mr = mn + h * 256;
    float s = 0;
#pragma unroll 8
    for (int c = 0; c < 256; ++c) s += wr[c] * mr[c];
    s += __shfl_xor(s, 1);
    if (h == 0) (sel ? corr_k : corr_q)[b * 128 + p] = s;
  } else {
    int blk = bid - 1552;                  // 0..2047
    int b = blk >> 8, mblk = blk & 255;
    int lane = t & 63, wv4 = t >> 6;
    int m = mblk * 4 + wv4;
    bf16x8 h8 = *(const bf16x8*)(xdt + ((size_t)b * 1024 + m) * 512 + lane * 8);
    const float* wmr = wm + lane * 8;
    float s = 0;
#pragma unroll
    for (int j = 0; j < 8; ++j) s += b2f((u16)h8[j]) * wmr[j];
    s = waveRedSum(s);
    if (lane == 0) logits[b * 1024 + m] = s + bm[0];
  }
}

// ---------------------------------------------------------------------------
// Kernel 3: bf16 GEMM  D[row][col] = A[row][:] . Bt[col][:]  (k = 512)
// A: weights [Cout][512]; Bt: xt/xdt [b][Ncols][512]. BRxBC tile, 4 waves 2x2.
// TRANS: out[b][col][Cout] (q, kt); else out[b][row][Ncols] (v).
// CORR: subtract corr[b][row] pre-cast (folds the q/k mean-centering).
// ---------------------------------------------------------------------------
template <int BR, int BC, bool TRANS, bool CORR>
__global__ __launch_bounds__(256) void gemm_bt(const u16* __restrict__ A,
                                               const u16* __restrict__ Bt,
                                               const float* __restrict__ corr,
                                               u16* __restrict__ outp,
                                               int Cout, int Ncols) {
  constexpr int WR = BR / 2, WC = BC / 2, ITR = WR / 16, ITC = WC / 16;
  constexpr int AFR = BR * 8 / 256, BFR = BC * 8 / 256;
  const int b = blockIdx.z;
  const int col0 = blockIdx.x * BC;
  const int row0 = blockIdx.y * BR;
  const int tid = threadIdx.x;
  const int lane = tid & 63, wid = tid >> 6;
  const int g = lane >> 4, c16 = lane & 15;
  const int wr = (wid >> 1) * WR, wc = (wid & 1) * WC;
  __shared__ __align__(16) u16 As[BR][72];
  __shared__ __align__(16) u16 Bs[BC][72];
  const u16* Bb = Bt + (size_t)b * Ncols * 512;
  f32x4 acc[ITR][ITC];
#pragma unroll
  for (int i = 0; i < ITR; ++i)
#pragma unroll
    for (int j = 0; j < ITC; ++j) acc[i][j] = (f32x4){0.f, 0.f, 0.f, 0.f};

  for (int k0 = 0; k0 < 512; k0 += 64) {
#pragma unroll
    for (int i = 0; i < AFR; ++i) {
      int f = tid + i * 256;
      int r = f >> 3, c8 = f & 7;
      *(bf16x8*)&As[r][c8 * 8] =
          *(const bf16x8*)(A + (size_t)(row0 + r) * 512 + k0 + c8 * 8);
    }
#pragma unroll
    for (int i = 0; i < BFR; ++i) {
      int f = tid + i * 256;
      int r = f >> 3, c8 = f & 7;
      *(bf16x8*)&Bs[r][c8 * 8] =
          *(const bf16x8*)(Bb + (size_t)(col0 + r) * 512 + k0 + c8 * 8);
    }
    __syncthreads();
#pragma unroll
    for (int kk = 0; kk < 2; ++kk) {
      bf16x8 bfr[ITC];
#pragma unroll
      for (int j = 0; j < ITC; ++j)
        bfr[j] = *(const bf16x8*)&Bs[wc + j * 16 + c16][kk * 32 + g * 8];
#pragma unroll
      for (int i = 0; i < ITR; ++i) {
        bf16x8 af = *(const bf16x8*)&As[wr + i * 16 + c16][kk * 32 + g * 8];
#pragma unroll
        for (int j = 0; j < ITC; ++j)
          acc[i][j] = MFMA(af, bfr[j], acc[i][j], 0, 0, 0);
      }
    }
    __syncthreads();
  }
  if (TRANS) {
#pragma unroll
    for (int i = 0; i < ITR; ++i)
#pragma unroll
      for (int j = 0; j < ITC; ++j) {
        int row = row0 + wr + i * 16 + g * 4;
        int col = col0 + wc + j * 16 + c16;
        s16x4 h;
#pragma unroll
        for (int r = 0; r < 4; ++r) {
          float val = acc[i][j][r];
          if (CORR) val -= corr[b * 128 + row + r];
          h[r] = (short)f2b(val);
        }
        *(s16x4*)(outp + ((size_t)b * Ncols + col) * Cout + row) = h;
      }
  } else {
#pragma unroll
    for (int i = 0; i < ITR; ++i)
#pragma unroll
      for (int j = 0; j < ITC; ++j) {
        int row = row0 + wr + i * 16 + g * 4;
        int col = col0 + wc + j * 16 + c16;
#pragma unroll
        for (int r = 0; r < 4; ++r)
          outp[((size_t)b * Cout + row + r) * Ncols + col] = f2b(acc[i][j][r]);
      }
  }
}

// ---------------------------------------------------------------------------
// Kernel 4: softmax(logits) (redundant per block) + gc[b][c] = v . p
// ---------------------------------------------------------------------------
__global__ __launch_bounds__(256) void k_gc(const float* __restrict__ logits,
                                            const u16* __restrict__ v,
                                            float* __restrict__ gc) {
  const int b = blockIdx.x >> 4, cc = blockIdx.x & 15;
  const int tid = threadIdx.x;
  const int lane = tid & 63, wid = tid >> 6;
  __shared__ float pl[1024];
  __shared__ float r4[4];
  __shared__ float stot[2];
  float4 lv = *(const float4*)&logits[b * 1024 + tid * 4];
  float mx = fmaxf(fmaxf(lv.x, lv.y), fmaxf(lv.z, lv.w));
#pragma unroll
  for (int off = 32; off > 0; off >>= 1) mx = fmaxf(mx, __shfl_xor(mx, off));
  if (lane == 0) r4[wid] = mx;
  __syncthreads();
  if (tid == 0) stot[0] = fmaxf(fmaxf(r4[0], r4[1]), fmaxf(r4[2], r4[3]));
  __syncthreads();
  const float M = stot[0];
  float e0 = __expf(lv.x - M), e1 = __expf(lv.y - M);
  float e2 = __expf(lv.z - M), e3 = __expf(lv.w - M);
  pl[tid * 4 + 0] = e0; pl[tid * 4 + 1] = e1;
  pl[tid * 4 + 2] = e2; pl[tid * 4 + 3] = e3;
  float ps = waveRedSum((e0 + e1) + (e2 + e3));
  if (lane == 0) r4[wid] = ps;
  __syncthreads();
  if (tid == 0) stot[1] = 1.0f / (r4[0] + r4[1] + r4[2] + r4[3]);
  __syncthreads();
  const float inv = stot[1];
  const int c = cc * 32 + (tid >> 3), sub = tid & 7;
  const u16* vr = v + ((size_t)b * 512 + c) * 1024 + sub * 128;
  const float* plr = pl + sub * 128;
  float s = 0;
#pragma unroll
  for (int i = 0; i < 16; ++i) {
    bf16x8 h = *(const bf16x8*)(vr + i * 8);
#pragma unroll
    for (int j = 0; j < 8; ++j) s += b2f((u16)h[j]) * plr[i * 8 + j];
  }
  s += __shfl_xor(s, 1);
  s += __shfl_xor(s, 2);
  s += __shfl_xor(s, 4);
  if (sub == 0) gc[b * 512 + c] = s * inv;
}

// ---------------------------------------------------------------------------
// S-phase helper: 8 MFMA S^T tile -> exp2 -> pack -> ds_write P (swizzled).
// ---------------------------------------------------------------------------
__device__ __forceinline__ void s_phase(const bf16x8* kbf, const bf16x8 (&qf)[2][4],
                                        u16* PlBuf, int nA, int o,
                                        float& lp0, float& lp1) {
  f32x4 sv0 = (f32x4){0.f, 0.f, 0.f, 0.f};
  f32x4 sv1 = (f32x4){0.f, 0.f, 0.f, 0.f};
#pragma unroll
  for (int kf = 0; kf < 4; ++kf) {
    sv0 = MFMA(kbf[kf], qf[0][kf], sv0, 0, 0, 0);
    sv1 = MFMA(kbf[kf], qf[1][kf], sv1, 0, 0, 0);
  }
  float p00 = exp2f(fmaf(sv0[0], A2C, -B2C));
  float p01 = exp2f(fmaf(sv0[1], A2C, -B2C));
  float p02 = exp2f(fmaf(sv0[2], A2C, -B2C));
  float p03 = exp2f(fmaf(sv0[3], A2C, -B2C));
  float p10 = exp2f(fmaf(sv1[0], A2C, -B2C));
  float p11 = exp2f(fmaf(sv1[1], A2C, -B2C));
  float p12 = exp2f(fmaf(sv1[2], A2C, -B2C));
  float p13 = exp2f(fmaf(sv1[3], A2C, -B2C));
  lp0 += (p00 + p01) + (p02 + p03);
  lp1 += (p10 + p11) + (p12 + p13);
  uint2 w0, w1;
  w0.x = (unsigned)f2b(p00) | ((unsigned)f2b(p01) << 16);
  w0.y = (unsigned)f2b(p02) | ((unsigned)f2b(p03) << 16);
  w1.x = (unsigned)f2b(p10) | ((unsigned)f2b(p11) << 16);
  w1.y = (unsigned)f2b(p12) | ((unsigned)f2b(p13) << 16);
  *(uint2*)&PlBuf[nA * 64 + o] = w0;
  *(uint2*)&PlBuf[(nA + 16) * 64 + o] = w1;
}

// ---------------------------------------------------------------------------
// Kernel 5: flash attention, single-barrier rotated pipeline.
// 512 thr = 8 waves; QB=64; grid 512: b=bid&7 (XCD), n0=(bid>>3)*64.
// iter s: [issue K(s+2)] vmcnt(4) lgkm(0) | barrier | [issue V(s+1) gload_lds]
//         PV(s) {Pl[par],Vl[par]}  ||  S(s+1) -> Pl[nxt]   (compiler interleaves)
// Dbuf: Vl 2x64KB, Pl 2x8KB. All X-swizzled (T2 via pre-swizzled gload source).
// ---------------------------------------------------------------------------
__global__ __launch_bounds__(512, 2) void attn(const u16* __restrict__ q,
                                               const u16* __restrict__ kt,
                                               const u16* __restrict__ v,
                                               const float* __restrict__ gc,
                                               const float* __restrict__ x,
                                               const float* __restrict__ gamma,
                                               float* __restrict__ out) {
  extern __shared__ __align__(16) char smem[];
  u16* Vl = (u16*)smem;                   // 2 x 32768 halves (128 KB)
  u16* Pl = (u16*)(smem + 131072);        // 2 x 4096 halves (16 KB)
  float* l_s = (float*)(smem + 147456);   // 256 floats
  const int bid = blockIdx.x;
  const int b = bid & 7;
  const int n0 = (bid >> 3) * 64;
  const int tid = threadIdx.x;
  const int lane = tid & 63, wid = tid >> 6;
  const int g = lane >> 4, c16 = lane & 15;
  const int mb = wid & 3, nh = wid >> 2;
  const int xsw = (c16 & 7) << 3;
  const int nA = nh * 32 + c16;
  const int po = (mb * 16 + g * 4) ^ xsw;

  bf16x8 qf[2][4];
  {
    const u16* qr = q + ((size_t)b * N_ + n0 + nh * 32 + c16) * P_ + g * 8;
#pragma unroll
    for (int t = 0; t < 2; ++t)
#pragma unroll
      for (int kf = 0; kf < 4; ++kf)
        qf[t][kf] = *(const bf16x8*)(qr + t * 16 * P_ + kf * 32);
  }
  const u16* ktr = kt + ((size_t)b * M_ + mb * 16 + c16) * P_ + g * 8;
  bf16x8 kb[2][4];
#pragma unroll
  for (int kf = 0; kf < 4; ++kf) kb[0][kf] = *(const bf16x8*)(ktr + kf * 32);
#pragma unroll
  for (int kf = 0; kf < 4; ++kf) kb[1][kf] = *(const bf16x8*)(ktr + 64 * P_ + kf * 32);
  const u16* vst = v + ((size_t)b * C_ + wid * 64 + (lane >> 3)) * M_ +
                   ((lane & 7) ^ (lane >> 3)) * 8;
#pragma unroll
  for (int i = 0; i < 8; ++i)
    gload_lds16(vst + (size_t)i * 8 * M_, Vl + (wid * 8 + i) * 512);

  float lp0 = 0.f, lp1 = 0.f;
  s_phase(kb[0], qf, Pl, nA, po, lp0, lp1);   // P(0) -> Pl[0]

  f32x4 acc[4][4];
#pragma unroll
  for (int i = 0; i < 4; ++i)
#pragma unroll
    for (int j = 0; j < 4; ++j) acc[i][j] = (f32x4){0.f, 0.f, 0.f, 0.f};

#pragma unroll 2
  for (int s = 0; s < 16; ++s) {
    const int par = s & 1, nxt = par ^ 1;
    if (s < 14) {
      const size_t moff = (size_t)(s + 2) * 64 * P_;
#pragma unroll
      for (int kf = 0; kf < 4; ++kf)
        kb[par][kf] = *(const bf16x8*)(ktr + moff + kf * 32);
      asm volatile("s_waitcnt vmcnt(4) lgkmcnt(0)" ::: "memory");
    } else {
      asm volatile("s_waitcnt vmcnt(0) lgkmcnt(0)" ::: "memory");
    }
    __builtin_amdgcn_sched_barrier(0);
    __builtin_amdgcn_s_barrier();
    __builtin_amdgcn_sched_barrier(0);
    if (s < 15) {
      const int m1 = (s + 1) * 64;
#pragma unroll
      for (int i = 0; i < 8; ++i)
        gload_lds16(vst + m1 + (size_t)i * 8 * M_,
                    Vl + nxt * 32768 + (wid * 8 + i) * 512);
    }
    // ---- PV(s) ----
    const u16* VlP = Vl + par * 32768;
    const u16* PlP = Pl + par * 4096;
#pragma unroll
    for (int kk = 0; kk < 2; ++kk) {
      bf16x8 pb[4];
#pragma unroll
      for (int nb = 0; nb < 4; ++nb)
        pb[nb] = *(const bf16x8*)&PlP[(nb * 16 + c16) * 64 + ((kk * 32 + g * 8) ^ xsw)];
#pragma unroll
      for (int cf = 0; cf < 4; ++cf) {
        bf16x8 va = *(const bf16x8*)&VlP[(wid * 64 + cf * 16 + c16) * 64 +
                                         ((kk * 32 + g * 8) ^ xsw)];
#pragma unroll
        for (int nb = 0; nb < 4; ++nb)
          acc[cf][nb] = MFMA(va, pb[nb], acc[cf][nb], 0, 0, 0);
      }
    }
    // ---- S(s+1) -> Pl[nxt] ----
    if (s < 15) s_phase(kb[nxt], qf, Pl + nxt * 4096, nA, po, lp0, lp1);
  }

  // ---- l reduction ----
  lp0 += __shfl_xor(lp0, 16); lp0 += __shfl_xor(lp0, 32);
  lp1 += __shfl_xor(lp1, 16); lp1 += __shfl_xor(lp1, 32);
  if (lane < 16) {
    l_s[mb * 64 + nh * 32 + lane] = lp0;
    l_s[mb * 64 + nh * 32 + 16 + lane] = lp1;
  }
  __syncthreads();
  float linv[4];
#pragma unroll
  for (int nb = 0; nb < 4; ++nb) {
    int n = nb * 16 + c16;
    linv[nb] = 1.0f / (l_s[n] + l_s[64 + n] + l_s[128 + n] + l_s[192 + n]);
  }
  const float gam = gamma[0];
#pragma unroll
  for (int cf = 0; cf < 4; ++cf) {
    const int c = wid * 64 + cf * 16 + g * 4;
    float gcv[4];
#pragma unroll
    for (int r = 0; r < 4; ++r) gcv[r] = gc[b * C_ + c + r];
#pragma unroll
    for (int nb = 0; nb < 4; ++nb) {
      const size_t idx0 = ((size_t)b * C_ + c) * (size_t)N_ + n0 + nb * 16 + c16;
#pragma unroll
      for (int r = 0; r < 4; ++r) {
        const size_t idx = idx0 + (size_t)r * N_;
        out[idx] = gam * acc[cf][nb][r] * linv[nb] + gcv[r] + x[idx];
      }
    }
  }
}

// ---------------------------------------------------------------------------
extern "C" void kernel_launch(void* const* d_in, const int* in_sizes, int n_in,
                              void* d_out, int out_size, void* d_ws, size_t ws_size,
                              hipStream_t stream) {
  const float* x     = (const float*)d_in[0];
  const float* wq    = (const float*)d_in[1];
  const float* wk    = (const float*)d_in[3];
  const float* wv    = (const float*)d_in[5];
  const float* wm    = (const float*)d_in[6];
  const float* bm    = (const float*)d_in[7];
  const float* gamma = (const float*)d_in[8];
  float* out = (float*)d_out;
  char* ws = (char*)d_ws;

  u16*   xt     = (u16*)(ws + 0);          // 33,554,432
  u16*   xdt    = (u16*)(ws + 33554432);   //  8,388,608
  u16*   q_ws   = (u16*)(ws + 41943040);   //  8,388,608  [b][n][p]
  u16*   kt_ws  = (u16*)(ws + 50331648);   //  2,097,152  [b][m][p]
  u16*   v_ws   = (u16*)(ws + 52428800);   //  8,388,608  [b][c][m]
  u16*   wq_b   = (u16*)(ws + 60817408);   //    131,072
  u16*   wk_b   = (u16*)(ws + 60948480);   //    131,072
  u16*   wv_b   = (u16*)(ws + 61079552);   //    524,288
  float* meanx  = (float*)(ws + 61603840); //     16,384
  float* meanxd = (float*)(ws + 61620224); //     16,384
  float* corr_q = (float*)(ws + 61636608); //      4,096
  float* corr_k = (float*)(ws + 61640704); //      4,096
  float* gc     = (float*)(ws + 61644800); //     16,384
  float* logits = (float*)(ws + 61661184); //     32,768

  hipMemsetAsync(ws + 61603840, 0, 32768, stream);   // zero meanx+meanxd
  prep_tx<<<dim3(2048), dim3(256), 0, stream>>>(x, xt, xdt, meanx, meanxd);
  wcvt<<<dim3(3600), dim3(256), 0, stream>>>(wq, wk, wv, wm, bm, meanx, meanxd,
                                             xdt, wq_b, wk_b, wv_b, corr_q,
                                             corr_k, logits);
  gemm_bt<128, 128, true, true><<<dim3(32, 1, B_), dim3(256), 0, stream>>>(
      wq_b, xt, corr_q, q_ws, 128, 4096);
  gemm_bt<128, 64, true, true><<<dim3(16, 1, B_), dim3(256), 0, stream>>>(
      wk_b, xdt, corr_k, kt_ws, 128, 1024);
  gemm_bt<128, 128, false, false><<<dim3(8, 4, B_), dim3(256), 0, stream>>>(
      wv_b, xdt, nullptr, v_ws, 512, 1024);
  k_gc<<<dim3(128), dim3(256), 0, stream>>>(logits, v_ws, gc);

  hipFuncSetAttribute((const void*)attn,
                      hipFuncAttributeMaxDynamicSharedMemorySize, 148480);
  attn<<<dim3(512), dim3(512), 148480, stream>>>(q_ws, kt_ws, v_ws, gc, x,
                                                 gamma, out);
}